// Round 1
// baseline (1183.017 us; speedup 1.0000x reference)
//
#include <hip/hip_runtime.h>
#include <cstdint>
#include <cstddef>

#define TPB 256
#define BM 64
#define BK 32

// ---------------------------------------------------------------------------
// pre: per-node phase.
//   hidden = relu(x @ h_w1 + h_b1)            [row,128]
//   delta  = tanh(hidden @ h_w2 + h_b2)       [row,3]
//   A2[j]  = x_j @ f_w[3:,:] + pos_j @ f_w[:3,:]
//   B[i]   = (delta_i - pos_i) @ f_w[:3,:] + f_b
// Tiled GEMM: 64 rows/block, 256 threads, each thread 8 rows x 4 cols,
// two accumulator sets (h_w1 and f_w_x share the x tile).
// ---------------------------------------------------------------------------
__global__ __launch_bounds__(TPB) void pre_kernel(
    const float* __restrict__ x, const float* __restrict__ pos,
    const float* __restrict__ h_w1, const float* __restrict__ h_b1,
    const float* __restrict__ h_w2, const float* __restrict__ h_b2,
    const float* __restrict__ f_w, const float* __restrict__ f_b,
    float* __restrict__ A2, float* __restrict__ Bv, int M)
{
    __shared__ float smem[BM * BK + 2 * BK * 128]; // 10240 floats = 40 KB
    float* xs  = smem;                  // [BM][BK]
    float* w1s = smem + BM * BK;        // [BK][128]
    float* w2s = smem + BM * BK + BK * 128;

    const int tid = threadIdx.x;
    const int tx = tid & 31;
    const int ty = tid >> 5;
    const int row0 = blockIdx.x * BM;

    float acc_h[8][4];
    float acc_a[8][4];
#pragma unroll
    for (int r = 0; r < 8; ++r)
#pragma unroll
        for (int c = 0; c < 4; ++c) { acc_h[r][c] = 0.f; acc_a[r][c] = 0.f; }

    for (int k0 = 0; k0 < 128; k0 += BK) {
        // load x tile [64][32]
        for (int i = tid; i < BM * BK / 4; i += TPB) {
            int r  = i >> 3;
            int c4 = (i & 7) << 2;
            int rr = row0 + r; if (rr >= M) rr = M - 1;
            float4 v = *(const float4*)(x + (size_t)rr * 128 + k0 + c4);
            xs[r * BK + c4 + 0] = v.x;
            xs[r * BK + c4 + 1] = v.y;
            xs[r * BK + c4 + 2] = v.z;
            xs[r * BK + c4 + 3] = v.w;
        }
        // load weight tiles [32][128] for h_w1 and f_w_x (rows 3..)
        for (int i = tid; i < BK * 128 / 4; i += TPB) {
            int r  = i >> 5;
            int c4 = (i & 31) << 2;
            *(float4*)(w1s + r * 128 + c4) =
                *(const float4*)(h_w1 + (size_t)(k0 + r) * 128 + c4);
            *(float4*)(w2s + r * 128 + c4) =
                *(const float4*)(f_w + (size_t)(3 + k0 + r) * 128 + c4);
        }
        __syncthreads();
#pragma unroll
        for (int k = 0; k < BK; ++k) {
            float4 w1v = *(const float4*)(w1s + k * 128 + tx * 4);
            float4 w2v = *(const float4*)(w2s + k * 128 + tx * 4);
#pragma unroll
            for (int r = 0; r < 8; ++r) {
                float xv = xs[(ty * 8 + r) * BK + k];
                acc_h[r][0] += xv * w1v.x; acc_h[r][1] += xv * w1v.y;
                acc_h[r][2] += xv * w1v.z; acc_h[r][3] += xv * w1v.w;
                acc_a[r][0] += xv * w2v.x; acc_a[r][1] += xv * w2v.y;
                acc_a[r][2] += xv * w2v.z; acc_a[r][3] += xv * w2v.w;
            }
        }
        __syncthreads();
    }

    // epilogue: hidden -> LDS, delta, then A2/B
    float* hid = smem;            // [BM][129] = 8256 floats
    float* dl  = smem + BM * 129; // [BM][4]
    {
        float b0 = h_b1[tx * 4 + 0], b1 = h_b1[tx * 4 + 1];
        float b2 = h_b1[tx * 4 + 2], b3 = h_b1[tx * 4 + 3];
#pragma unroll
        for (int r = 0; r < 8; ++r) {
            int row = ty * 8 + r;
            hid[row * 129 + tx * 4 + 0] = fmaxf(acc_h[r][0] + b0, 0.f);
            hid[row * 129 + tx * 4 + 1] = fmaxf(acc_h[r][1] + b1, 0.f);
            hid[row * 129 + tx * 4 + 2] = fmaxf(acc_h[r][2] + b2, 0.f);
            hid[row * 129 + tx * 4 + 3] = fmaxf(acc_h[r][3] + b3, 0.f);
        }
    }
    __syncthreads();
    if (tid < 192) {
        int row = tid & 63;
        int d   = tid >> 6;       // 0..2
        float s = h_b2[d];
        for (int k = 0; k < 128; ++k)
            s += hid[row * 129 + k] * h_w2[k * 3 + d];
        dl[row * 4 + d] = tanhf(s);
    }
    __syncthreads();

#pragma unroll
    for (int r = 0; r < 8; ++r) {
        int row  = ty * 8 + r;
        int grow = row0 + row;
        if (grow < M) {
            float p0 = pos[(size_t)grow * 3 + 0];
            float p1 = pos[(size_t)grow * 3 + 1];
            float p2 = pos[(size_t)grow * 3 + 2];
            float e0 = dl[row * 4 + 0];
            float e1 = dl[row * 4 + 1];
            float e2 = dl[row * 4 + 2];
            float4 av, bv;
#pragma unroll
            for (int c = 0; c < 4; ++c) {
                int col = tx * 4 + c;
                float w0 = f_w[col];
                float w1 = f_w[128 + col];
                float w2 = f_w[256 + col];
                float pw = p0 * w0 + p1 * w1 + p2 * w2;
                float dw = e0 * w0 + e1 * w1 + e2 * w2;
                ((float*)&av)[c] = acc_a[r][c] + pw;
                ((float*)&bv)[c] = f_b[col] + dw - pw;
            }
            *(float4*)(A2 + (size_t)grow * 128 + tx * 4) = av;
            *(float4*)(Bv + (size_t)grow * 128 + tx * 4) = bv;
        }
    }
}

// ---------------------------------------------------------------------------
// edge: m = relu(A2[src] + B[dst]); aggr[dst] += m   (fp32 atomics)
// 32 lanes per edge, float4 per lane.
// ---------------------------------------------------------------------------
__global__ __launch_bounds__(TPB) void edge_kernel(
    const int* __restrict__ ei, const float* __restrict__ A2,
    const float* __restrict__ Bv, float* __restrict__ aggr, int E)
{
    int e = blockIdx.x * 8 + (threadIdx.x >> 5);
    if (e >= E) return;
    int lane = threadIdx.x & 31;
    int src = ei[e];
    int dst = ei[E + e];
    float4 a = *(const float4*)(A2 + (size_t)src * 128 + lane * 4);
    float4 b = *(const float4*)(Bv + (size_t)dst * 128 + lane * 4);
    float4 m;
    m.x = fmaxf(a.x + b.x, 0.f);
    m.y = fmaxf(a.y + b.y, 0.f);
    m.z = fmaxf(a.z + b.z, 0.f);
    m.w = fmaxf(a.w + b.w, 0.f);
    float* p = aggr + (size_t)dst * 128 + lane * 4;
    atomicAdd(p + 0, m.x);
    atomicAdd(p + 1, m.y);
    atomicAdd(p + 2, m.z);
    atomicAdd(p + 3, m.w);
}

// ---------------------------------------------------------------------------
// post: out = relu(aggr @ g_w1 + g_b1) @ g_w2 + g_b2 + x
// aggr lives in d_out; each block reads its own 64 rows then overwrites them.
// ---------------------------------------------------------------------------
__global__ __launch_bounds__(TPB) void post_kernel(
    const float* __restrict__ x,
    const float* __restrict__ g_w1, const float* __restrict__ g_b1,
    const float* __restrict__ g_w2, const float* __restrict__ g_b2,
    float* __restrict__ out, int M)
{
    __shared__ float smem[BM * 129 + BK * 128]; // 12352 floats = 49.4 KB
    float* xs = smem;            // GEMM1 aggr tile [BM][BK]
    float* ws = smem + BM * BK;  // GEMM1 weight tile [BK][128]

    const int tid = threadIdx.x;
    const int tx = tid & 31;
    const int ty = tid >> 5;
    const int row0 = blockIdx.x * BM;

    float acc[8][4];
#pragma unroll
    for (int r = 0; r < 8; ++r)
#pragma unroll
        for (int c = 0; c < 4; ++c) acc[r][c] = 0.f;

    for (int k0 = 0; k0 < 128; k0 += BK) {
        for (int i = tid; i < BM * BK / 4; i += TPB) {
            int r  = i >> 3;
            int c4 = (i & 7) << 2;
            int rr = row0 + r; if (rr >= M) rr = M - 1;
            float4 v = *(const float4*)(out + (size_t)rr * 128 + k0 + c4);
            xs[r * BK + c4 + 0] = v.x;
            xs[r * BK + c4 + 1] = v.y;
            xs[r * BK + c4 + 2] = v.z;
            xs[r * BK + c4 + 3] = v.w;
        }
        for (int i = tid; i < BK * 128 / 4; i += TPB) {
            int r  = i >> 5;
            int c4 = (i & 31) << 2;
            *(float4*)(ws + r * 128 + c4) =
                *(const float4*)(g_w1 + (size_t)(k0 + r) * 128 + c4);
        }
        __syncthreads();
#pragma unroll
        for (int k = 0; k < BK; ++k) {
            float4 wv = *(const float4*)(ws + k * 128 + tx * 4);
#pragma unroll
            for (int r = 0; r < 8; ++r) {
                float xv = xs[(ty * 8 + r) * BK + k];
                acc[r][0] += xv * wv.x; acc[r][1] += xv * wv.y;
                acc[r][2] += xv * wv.z; acc[r][3] += xv * wv.w;
            }
        }
        __syncthreads();
    }

    // hidden2 = relu(acc + g_b1) -> LDS [BM][129]
    float* hid = smem;            // 8256 floats
    float* w2s = smem + BM * 129; // [BK][128]
    {
        float b0 = g_b1[tx * 4 + 0], b1 = g_b1[tx * 4 + 1];
        float b2 = g_b1[tx * 4 + 2], b3 = g_b1[tx * 4 + 3];
#pragma unroll
        for (int r = 0; r < 8; ++r) {
            int row = ty * 8 + r;
            hid[row * 129 + tx * 4 + 0] = fmaxf(acc[r][0] + b0, 0.f);
            hid[row * 129 + tx * 4 + 1] = fmaxf(acc[r][1] + b1, 0.f);
            hid[row * 129 + tx * 4 + 2] = fmaxf(acc[r][2] + b2, 0.f);
            hid[row * 129 + tx * 4 + 3] = fmaxf(acc[r][3] + b3, 0.f);
        }
    }
    __syncthreads();

    float acc2[8][4];
#pragma unroll
    for (int r = 0; r < 8; ++r)
#pragma unroll
        for (int c = 0; c < 4; ++c) acc2[r][c] = 0.f;

    for (int k0 = 0; k0 < 128; k0 += BK) {
        for (int i = tid; i < BK * 128 / 4; i += TPB) {
            int r  = i >> 5;
            int c4 = (i & 31) << 2;
            *(float4*)(w2s + r * 128 + c4) =
                *(const float4*)(g_w2 + (size_t)(k0 + r) * 128 + c4);
        }
        __syncthreads();
#pragma unroll
        for (int k = 0; k < BK; ++k) {
            float4 wv = *(const float4*)(w2s + k * 128 + tx * 4);
#pragma unroll
            for (int r = 0; r < 8; ++r) {
                float xv = hid[(ty * 8 + r) * 129 + k0 + k];
                acc2[r][0] += xv * wv.x; acc2[r][1] += xv * wv.y;
                acc2[r][2] += xv * wv.z; acc2[r][3] += xv * wv.w;
            }
        }
        __syncthreads();
    }

    float b0 = g_b2[tx * 4 + 0], b1 = g_b2[tx * 4 + 1];
    float b2 = g_b2[tx * 4 + 2], b3 = g_b2[tx * 4 + 3];
#pragma unroll
    for (int r = 0; r < 8; ++r) {
        int grow = row0 + ty * 8 + r;
        if (grow < M) {
            float4 xv = *(const float4*)(x + (size_t)grow * 128 + tx * 4);
            float4 ov;
            ov.x = acc2[r][0] + b0 + xv.x;
            ov.y = acc2[r][1] + b1 + xv.y;
            ov.z = acc2[r][2] + b2 + xv.z;
            ov.w = acc2[r][3] + b3 + xv.w;
            *(float4*)(out + (size_t)grow * 128 + tx * 4) = ov;
        }
    }
}

extern "C" void kernel_launch(void* const* d_in, const int* in_sizes, int n_in,
                              void* d_out, int out_size, void* d_ws, size_t ws_size,
                              hipStream_t stream)
{
    const float* x    = (const float*)d_in[0];
    const float* pos  = (const float*)d_in[1];
    const int*   ei   = (const int*)d_in[2];
    const float* h_w1 = (const float*)d_in[3];
    const float* h_b1 = (const float*)d_in[4];
    const float* h_w2 = (const float*)d_in[5];
    const float* h_b2 = (const float*)d_in[6];
    const float* f_w  = (const float*)d_in[7];
    const float* f_b  = (const float*)d_in[8];
    const float* g_w1 = (const float*)d_in[9];
    const float* g_b1 = (const float*)d_in[10];
    const float* g_w2 = (const float*)d_in[11];
    const float* g_b2 = (const float*)d_in[12];

    const int M = in_sizes[1] / 3;       // 50000 nodes
    const int E = in_sizes[2] / 2;       // 600000 edges

    float* A2 = (float*)d_ws;                      // [M][128]
    float* Bv = A2 + (size_t)M * 128;              // [M][128]
    float* out = (float*)d_out;                    // doubles as aggr

    const int nb = (M + BM - 1) / BM;

    hipMemsetAsync(out, 0, (size_t)M * 128 * sizeof(float), stream);
    pre_kernel<<<nb, TPB, 0, stream>>>(x, pos, h_w1, h_b1, h_w2, h_b2,
                                       f_w, f_b, A2, Bv, M);
    edge_kernel<<<(E + 7) / 8, TPB, 0, stream>>>(ei, A2, Bv, out, E);
    post_kernel<<<nb, TPB, 0, stream>>>(x, g_w1, g_b1, g_w2, g_b2, out, M);
}

// Round 2
// 315.584 us; speedup vs baseline: 3.7487x; 3.7487x over previous
//
#include <hip/hip_runtime.h>
#include <cstdint>
#include <cstddef>

#define TPB 256
#define BM 64
#define BK 32

// ---------------------------------------------------------------------------
// pre: per-node phase.
//   hidden = relu(x @ h_w1 + h_b1)            [row,128]
//   delta  = tanh(hidden @ h_w2 + h_b2)       [row,3]
//   A2[j]  = x_j @ f_w[3:,:] + pos_j @ f_w[:3,:]
//   B[i]   = (delta_i - pos_i) @ f_w[:3,:] + f_b
// ---------------------------------------------------------------------------
__global__ __launch_bounds__(TPB) void pre_kernel(
    const float* __restrict__ x, const float* __restrict__ pos,
    const float* __restrict__ h_w1, const float* __restrict__ h_b1,
    const float* __restrict__ h_w2, const float* __restrict__ h_b2,
    const float* __restrict__ f_w, const float* __restrict__ f_b,
    float* __restrict__ A2, float* __restrict__ Bv, int M)
{
    __shared__ float smem[BM * BK + 2 * BK * 128]; // 10240 floats = 40 KB
    float* xs  = smem;                  // [BM][BK]
    float* w1s = smem + BM * BK;        // [BK][128]
    float* w2s = smem + BM * BK + BK * 128;

    const int tid = threadIdx.x;
    const int tx = tid & 31;
    const int ty = tid >> 5;
    const int row0 = blockIdx.x * BM;

    float acc_h[8][4];
    float acc_a[8][4];
#pragma unroll
    for (int r = 0; r < 8; ++r)
#pragma unroll
        for (int c = 0; c < 4; ++c) { acc_h[r][c] = 0.f; acc_a[r][c] = 0.f; }

    for (int k0 = 0; k0 < 128; k0 += BK) {
        for (int i = tid; i < BM * BK / 4; i += TPB) {
            int r  = i >> 3;
            int c4 = (i & 7) << 2;
            int rr = row0 + r; if (rr >= M) rr = M - 1;
            float4 v = *(const float4*)(x + (size_t)rr * 128 + k0 + c4);
            xs[r * BK + c4 + 0] = v.x;
            xs[r * BK + c4 + 1] = v.y;
            xs[r * BK + c4 + 2] = v.z;
            xs[r * BK + c4 + 3] = v.w;
        }
        for (int i = tid; i < BK * 128 / 4; i += TPB) {
            int r  = i >> 5;
            int c4 = (i & 31) << 2;
            *(float4*)(w1s + r * 128 + c4) =
                *(const float4*)(h_w1 + (size_t)(k0 + r) * 128 + c4);
            *(float4*)(w2s + r * 128 + c4) =
                *(const float4*)(f_w + (size_t)(3 + k0 + r) * 128 + c4);
        }
        __syncthreads();
#pragma unroll
        for (int k = 0; k < BK; ++k) {
            float4 w1v = *(const float4*)(w1s + k * 128 + tx * 4);
            float4 w2v = *(const float4*)(w2s + k * 128 + tx * 4);
#pragma unroll
            for (int r = 0; r < 8; ++r) {
                float xv = xs[(ty * 8 + r) * BK + k];
                acc_h[r][0] += xv * w1v.x; acc_h[r][1] += xv * w1v.y;
                acc_h[r][2] += xv * w1v.z; acc_h[r][3] += xv * w1v.w;
                acc_a[r][0] += xv * w2v.x; acc_a[r][1] += xv * w2v.y;
                acc_a[r][2] += xv * w2v.z; acc_a[r][3] += xv * w2v.w;
            }
        }
        __syncthreads();
    }

    // epilogue: hidden -> LDS, delta, then A2/B
    float* hid = smem;            // [BM][129] = 8256 floats
    float* dl  = smem + BM * 129; // [BM][4]
    {
        float b0 = h_b1[tx * 4 + 0], b1 = h_b1[tx * 4 + 1];
        float b2 = h_b1[tx * 4 + 2], b3 = h_b1[tx * 4 + 3];
#pragma unroll
        for (int r = 0; r < 8; ++r) {
            int row = ty * 8 + r;
            hid[row * 129 + tx * 4 + 0] = fmaxf(acc_h[r][0] + b0, 0.f);
            hid[row * 129 + tx * 4 + 1] = fmaxf(acc_h[r][1] + b1, 0.f);
            hid[row * 129 + tx * 4 + 2] = fmaxf(acc_h[r][2] + b2, 0.f);
            hid[row * 129 + tx * 4 + 3] = fmaxf(acc_h[r][3] + b3, 0.f);
        }
    }
    __syncthreads();
    if (tid < 192) {
        int row = tid & 63;
        int d   = tid >> 6;       // 0..2
        float s = h_b2[d];
        for (int k = 0; k < 128; ++k)
            s += hid[row * 129 + k] * h_w2[k * 3 + d];
        dl[row * 4 + d] = tanhf(s);
    }
    __syncthreads();

#pragma unroll
    for (int r = 0; r < 8; ++r) {
        int row  = ty * 8 + r;
        int grow = row0 + row;
        if (grow < M) {
            float p0 = pos[(size_t)grow * 3 + 0];
            float p1 = pos[(size_t)grow * 3 + 1];
            float p2 = pos[(size_t)grow * 3 + 2];
            float e0 = dl[row * 4 + 0];
            float e1 = dl[row * 4 + 1];
            float e2 = dl[row * 4 + 2];
            float4 av, bv;
#pragma unroll
            for (int c = 0; c < 4; ++c) {
                int col = tx * 4 + c;
                float w0 = f_w[col];
                float w1 = f_w[128 + col];
                float w2 = f_w[256 + col];
                float pw = p0 * w0 + p1 * w1 + p2 * w2;
                float dw = e0 * w0 + e1 * w1 + e2 * w2;
                ((float*)&av)[c] = acc_a[r][c] + pw;
                ((float*)&bv)[c] = f_b[col] + dw - pw;
            }
            *(float4*)(A2 + (size_t)grow * 128 + tx * 4) = av;
            *(float4*)(Bv + (size_t)grow * 128 + tx * 4) = bv;
        }
    }
}

// ---------------------------------------------------------------------------
// counting sort of edges by dst: hist -> scan -> scatter
// ---------------------------------------------------------------------------
__global__ __launch_bounds__(TPB) void hist_kernel(
    const int* __restrict__ ei, int* __restrict__ counts, int E)
{
    int e = blockIdx.x * TPB + threadIdx.x;
    if (e < E) atomicAdd(&counts[ei[E + e]], 1);
}

// single-workgroup exclusive scan of counts[0..M) -> offs, cursor; offs[M]=E
__global__ __launch_bounds__(1024) void scan_kernel(
    const int* __restrict__ counts, int* __restrict__ offs,
    int* __restrict__ cursor, int M)
{
    __shared__ int wsum[16];
    __shared__ int carry_s;
    const int tid  = threadIdx.x;
    const int lane = tid & 63;
    const int wid  = tid >> 6;
    if (tid == 0) carry_s = 0;
    __syncthreads();
    for (int base = 0; base < M; base += 1024) {
        int i = base + tid;
        int v = (i < M) ? counts[i] : 0;
        int s = v;
#pragma unroll
        for (int d = 1; d < 64; d <<= 1) {
            int t = __shfl_up(s, d);
            if (lane >= d) s += t;
        }
        if (lane == 63) wsum[wid] = s;
        __syncthreads();
        if (wid == 0) {
            int ws = (lane < 16) ? wsum[lane] : 0;
#pragma unroll
            for (int d = 1; d < 16; d <<= 1) {
                int t = __shfl_up(ws, d);
                if (lane >= d) ws += t;
            }
            if (lane < 16) wsum[lane] = ws;
        }
        __syncthreads();
        int carry = carry_s;
        int wprev = (wid > 0) ? wsum[wid - 1] : 0;
        int excl  = carry + wprev + (s - v);
        if (i < M) { offs[i] = excl; cursor[i] = excl; }
        __syncthreads();
        if (tid == 1023) carry_s = carry + wsum[15];
        __syncthreads();
    }
    if (tid == 0) offs[M] = carry_s;
}

__global__ __launch_bounds__(TPB) void scatter_kernel(
    const int* __restrict__ ei, int* __restrict__ cursor,
    int* __restrict__ ssrc, int E)
{
    int e = blockIdx.x * TPB + threadIdx.x;
    if (e >= E) return;
    int d = ei[E + e];
    int p = atomicAdd(&cursor[d], 1);
    ssrc[p] = ei[e];
}

// ---------------------------------------------------------------------------
// segmented reduce: one wave per dst row, 2 cols/lane.
//   aggr[i] = sum_{k in [offs[i],offs[i+1])} relu(A2[ssrc[k]] + B[i])
// ---------------------------------------------------------------------------
__global__ __launch_bounds__(TPB) void reduce_kernel(
    const int* __restrict__ offs, const int* __restrict__ ssrc,
    const float* __restrict__ A2, const float* __restrict__ Bv,
    float* __restrict__ out, int M)
{
    int row = blockIdx.x * 4 + (threadIdx.x >> 6);
    if (row >= M) return;
    int lane = threadIdx.x & 63;
    int c = lane * 2;
    float2 b = *(const float2*)(Bv + (size_t)row * 128 + c);
    float2 acc; acc.x = 0.f; acc.y = 0.f;
    int k  = offs[row];
    int k1 = offs[row + 1];
    for (; k + 1 < k1; k += 2) {
        int s0 = ssrc[k];
        int s1 = ssrc[k + 1];
        float2 a0 = *(const float2*)(A2 + (size_t)s0 * 128 + c);
        float2 a1 = *(const float2*)(A2 + (size_t)s1 * 128 + c);
        acc.x += fmaxf(a0.x + b.x, 0.f) + fmaxf(a1.x + b.x, 0.f);
        acc.y += fmaxf(a0.y + b.y, 0.f) + fmaxf(a1.y + b.y, 0.f);
    }
    if (k < k1) {
        int s0 = ssrc[k];
        float2 a0 = *(const float2*)(A2 + (size_t)s0 * 128 + c);
        acc.x += fmaxf(a0.x + b.x, 0.f);
        acc.y += fmaxf(a0.y + b.y, 0.f);
    }
    *(float2*)(out + (size_t)row * 128 + c) = acc;
}

// ---------------------------------------------------------------------------
// post: out = relu(aggr @ g_w1 + g_b1) @ g_w2 + g_b2 + x   (in-place on out)
// ---------------------------------------------------------------------------
__global__ __launch_bounds__(TPB) void post_kernel(
    const float* __restrict__ x,
    const float* __restrict__ g_w1, const float* __restrict__ g_b1,
    const float* __restrict__ g_w2, const float* __restrict__ g_b2,
    float* __restrict__ out, int M)
{
    __shared__ float smem[BM * 129 + BK * 128]; // 49.4 KB
    float* xs = smem;            // [BM][BK]
    float* ws = smem + BM * BK;  // [BK][128]

    const int tid = threadIdx.x;
    const int tx = tid & 31;
    const int ty = tid >> 5;
    const int row0 = blockIdx.x * BM;

    float acc[8][4];
#pragma unroll
    for (int r = 0; r < 8; ++r)
#pragma unroll
        for (int c = 0; c < 4; ++c) acc[r][c] = 0.f;

    for (int k0 = 0; k0 < 128; k0 += BK) {
        for (int i = tid; i < BM * BK / 4; i += TPB) {
            int r  = i >> 3;
            int c4 = (i & 7) << 2;
            int rr = row0 + r; if (rr >= M) rr = M - 1;
            float4 v = *(const float4*)(out + (size_t)rr * 128 + k0 + c4);
            xs[r * BK + c4 + 0] = v.x;
            xs[r * BK + c4 + 1] = v.y;
            xs[r * BK + c4 + 2] = v.z;
            xs[r * BK + c4 + 3] = v.w;
        }
        for (int i = tid; i < BK * 128 / 4; i += TPB) {
            int r  = i >> 5;
            int c4 = (i & 31) << 2;
            *(float4*)(ws + r * 128 + c4) =
                *(const float4*)(g_w1 + (size_t)(k0 + r) * 128 + c4);
        }
        __syncthreads();
#pragma unroll
        for (int k = 0; k < BK; ++k) {
            float4 wv = *(const float4*)(ws + k * 128 + tx * 4);
#pragma unroll
            for (int r = 0; r < 8; ++r) {
                float xv = xs[(ty * 8 + r) * BK + k];
                acc[r][0] += xv * wv.x; acc[r][1] += xv * wv.y;
                acc[r][2] += xv * wv.z; acc[r][3] += xv * wv.w;
            }
        }
        __syncthreads();
    }

    float* hid = smem;            // [BM][129]
    float* w2s = smem + BM * 129; // [BK][128]
    {
        float b0 = g_b1[tx * 4 + 0], b1 = g_b1[tx * 4 + 1];
        float b2 = g_b1[tx * 4 + 2], b3 = g_b1[tx * 4 + 3];
#pragma unroll
        for (int r = 0; r < 8; ++r) {
            int row = ty * 8 + r;
            hid[row * 129 + tx * 4 + 0] = fmaxf(acc[r][0] + b0, 0.f);
            hid[row * 129 + tx * 4 + 1] = fmaxf(acc[r][1] + b1, 0.f);
            hid[row * 129 + tx * 4 + 2] = fmaxf(acc[r][2] + b2, 0.f);
            hid[row * 129 + tx * 4 + 3] = fmaxf(acc[r][3] + b3, 0.f);
        }
    }
    __syncthreads();

    float acc2[8][4];
#pragma unroll
    for (int r = 0; r < 8; ++r)
#pragma unroll
        for (int c = 0; c < 4; ++c) acc2[r][c] = 0.f;

    for (int k0 = 0; k0 < 128; k0 += BK) {
        for (int i = tid; i < BK * 128 / 4; i += TPB) {
            int r  = i >> 5;
            int c4 = (i & 31) << 2;
            *(float4*)(w2s + r * 128 + c4) =
                *(const float4*)(g_w2 + (size_t)(k0 + r) * 128 + c4);
        }
        __syncthreads();
#pragma unroll
        for (int k = 0; k < BK; ++k) {
            float4 wv = *(const float4*)(w2s + k * 128 + tx * 4);
#pragma unroll
            for (int r = 0; r < 8; ++r) {
                float xv = hid[(ty * 8 + r) * 129 + k0 + k];
                acc2[r][0] += xv * wv.x; acc2[r][1] += xv * wv.y;
                acc2[r][2] += xv * wv.z; acc2[r][3] += xv * wv.w;
            }
        }
        __syncthreads();
    }

    float b0 = g_b2[tx * 4 + 0], b1 = g_b2[tx * 4 + 1];
    float b2 = g_b2[tx * 4 + 2], b3 = g_b2[tx * 4 + 3];
#pragma unroll
    for (int r = 0; r < 8; ++r) {
        int grow = row0 + ty * 8 + r;
        if (grow < M) {
            float4 xv = *(const float4*)(x + (size_t)grow * 128 + tx * 4);
            float4 ov;
            ov.x = acc2[r][0] + b0 + xv.x;
            ov.y = acc2[r][1] + b1 + xv.y;
            ov.z = acc2[r][2] + b2 + xv.z;
            ov.w = acc2[r][3] + b3 + xv.w;
            *(float4*)(out + (size_t)grow * 128 + tx * 4) = ov;
        }
    }
}

extern "C" void kernel_launch(void* const* d_in, const int* in_sizes, int n_in,
                              void* d_out, int out_size, void* d_ws, size_t ws_size,
                              hipStream_t stream)
{
    const float* x    = (const float*)d_in[0];
    const float* pos  = (const float*)d_in[1];
    const int*   ei   = (const int*)d_in[2];
    const float* h_w1 = (const float*)d_in[3];
    const float* h_b1 = (const float*)d_in[4];
    const float* h_w2 = (const float*)d_in[5];
    const float* h_b2 = (const float*)d_in[6];
    const float* f_w  = (const float*)d_in[7];
    const float* f_b  = (const float*)d_in[8];
    const float* g_w1 = (const float*)d_in[9];
    const float* g_b1 = (const float*)d_in[10];
    const float* g_w2 = (const float*)d_in[11];
    const float* g_b2 = (const float*)d_in[12];

    const int M = in_sizes[1] / 3;       // 50000 nodes
    const int E = in_sizes[2] / 2;       // 600000 edges

    float* A2     = (float*)d_ws;                          // [M][128]
    float* Bv     = A2 + (size_t)M * 128;                  // [M][128]
    int*   counts = (int*)(Bv + (size_t)M * 128);          // [M]
    int*   offs   = counts + M;                            // [M+1]
    int*   cursor = offs + (M + 1);                        // [M]
    int*   ssrc   = cursor + M;                            // [E]
    float* out    = (float*)d_out;                         // aggr then final

    const int nb = (M + BM - 1) / BM;

    hipMemsetAsync(counts, 0, (size_t)M * sizeof(int), stream);
    pre_kernel<<<nb, TPB, 0, stream>>>(x, pos, h_w1, h_b1, h_w2, h_b2,
                                       f_w, f_b, A2, Bv, M);
    hist_kernel<<<(E + TPB - 1) / TPB, TPB, 0, stream>>>(ei, counts, E);
    scan_kernel<<<1, 1024, 0, stream>>>(counts, offs, cursor, M);
    scatter_kernel<<<(E + TPB - 1) / TPB, TPB, 0, stream>>>(ei, cursor, ssrc, E);
    reduce_kernel<<<(M + 3) / 4, TPB, 0, stream>>>(offs, ssrc, A2, Bv, out, M);
    post_kernel<<<nb, TPB, 0, stream>>>(x, g_w1, g_b1, g_w2, g_b2, out, M);
}

// Round 3
// 188.849 us; speedup vs baseline: 6.2644x; 1.6711x over previous
//
#include <hip/hip_runtime.h>
#include <cstdint>
#include <cstddef>

#define TPB 256

using frag_ab = __attribute__((ext_vector_type(8))) short;  // 8 bf16
using f32x4   = __attribute__((ext_vector_type(4))) float;  // 4 fp32 acc

__device__ inline ushort f2b(float f) {
    uint u = __builtin_bit_cast(uint, f);
    u = (u + 0x7FFFu + ((u >> 16) & 1u)) >> 16;
    return (ushort)u;
}
__device__ inline float b2f_lo(uint u) { return __builtin_bit_cast(float, u << 16); }
__device__ inline float b2f_hi(uint u) { return __builtin_bit_cast(float, u & 0xFFFF0000u); }

// ---------------------------------------------------------------------------
// pack: fp32 [128][Ncol] weight -> bf16 MFMA B-fragment order.
// frag idx = ((ntile*4 + kstep)*64 + lane)*8 + j
// element  = W[rowoff + kstep*32 + (lane>>4)*8 + j][ntile*16 + (lane&15)]
// m: 0=h_w1, 1=f_w rows 3.., 2=g_w1, 3=g_w2
// ---------------------------------------------------------------------------
__global__ __launch_bounds__(TPB) void pack_kernel(
    const float* __restrict__ h_w1, const float* __restrict__ f_w,
    const float* __restrict__ g_w1, const float* __restrict__ g_w2,
    short* __restrict__ W1pk, short* __restrict__ Wfpk,
    short* __restrict__ G1pk, short* __restrict__ G2pk)
{
    int m   = blockIdx.y;
    int fid = blockIdx.x * TPB + threadIdx.x;     // 0..2047
    int lane = fid & 63, ks = (fid >> 6) & 3, nt = fid >> 8;
    const float* src; short* dst; int rowoff = 0;
    if      (m == 0) { src = h_w1; dst = W1pk; }
    else if (m == 1) { src = f_w;  dst = Wfpk; rowoff = 3; }
    else if (m == 2) { src = g_w1; dst = G1pk; }
    else             { src = g_w2; dst = G2pk; }
    int col   = nt * 16 + (lane & 15);
    int kbase = ks * 32 + ((lane >> 4) << 3);
    frag_ab f;
#pragma unroll
    for (int j = 0; j < 8; ++j)
        f[j] = (short)f2b(src[(size_t)(rowoff + kbase + j) * 128 + col]);
    *(frag_ab*)(dst + (((size_t)(nt * 4 + ks) * 64 + lane) << 3)) = f;
}

// ---------------------------------------------------------------------------
// pre: MFMA node phase.
//   hidden = relu(x@h_w1+b1) (fp32 acc), delta = tanh(hidden@h_w2+b2)
//   A2h[j] = bf16( x_j@f_w[3:] + pos_j@f_w[:3] )
//   Bvh[i] = bf16( (delta_i-pos_i)@f_w[:3] + f_b )
// 64 rows/block, 4 waves, 16 rows/wave. A staged in LDS bf16, XOR-swizzled.
// ---------------------------------------------------------------------------
__global__ __launch_bounds__(TPB) void pre_kernel(
    const float* __restrict__ x, const float* __restrict__ pos,
    const short* __restrict__ W1pk, const float* __restrict__ h_b1,
    const float* __restrict__ h_w2, const float* __restrict__ h_b2,
    const short* __restrict__ Wfpk, const float* __restrict__ f_w,
    const float* __restrict__ f_b,
    ushort* __restrict__ A2h, ushort* __restrict__ Bvh, int M)
{
    __shared__ short xs[64 * 128];   // 16 KB bf16 tile
    const int tid  = threadIdx.x;
    const int lane = tid & 63;
    const int wave = tid >> 6;
    const int row0 = blockIdx.x * 64;

    // stage x tile -> bf16 LDS, swizzled 16B slots: slot ^= (row&7)
#pragma unroll
    for (int i = 0; i < 4; ++i) {
        int id = i * TPB + tid;
        int r = id >> 4, slot = id & 15;
        int gr = row0 + r; if (gr >= M) gr = M - 1;
        const float* px = x + (size_t)gr * 128 + slot * 8;
        float4 v0 = *(const float4*)px;
        float4 v1 = *(const float4*)(px + 4);
        frag_ab f;
        f[0] = (short)f2b(v0.x); f[1] = (short)f2b(v0.y);
        f[2] = (short)f2b(v0.z); f[3] = (short)f2b(v0.w);
        f[4] = (short)f2b(v1.x); f[5] = (short)f2b(v1.y);
        f[6] = (short)f2b(v1.z); f[7] = (short)f2b(v1.w);
        *(frag_ab*)(xs + r * 128 + ((slot ^ (r & 7)) << 3)) = f;
    }
    __syncthreads();

    const int wr0 = wave * 16;
    f32x4 acch[8], acca[8];
#pragma unroll
    for (int nt = 0; nt < 8; ++nt) { acch[nt] = (f32x4)0.f; acca[nt] = (f32x4)0.f; }

#pragma unroll
    for (int ks = 0; ks < 4; ++ks) {
        int arow  = wr0 + (lane & 15);
        int aslot = ks * 4 + (lane >> 4);
        frag_ab a = *(const frag_ab*)(xs + arow * 128 + ((aslot ^ (arow & 7)) << 3));
#pragma unroll
        for (int nt = 0; nt < 8; ++nt) {
            frag_ab bh = *(const frag_ab*)(W1pk + (((nt * 4 + ks) * 64 + lane) << 3));
            acch[nt] = __builtin_amdgcn_mfma_f32_16x16x32_bf16(a, bh, acch[nt], 0, 0, 0);
            frag_ab bf = *(const frag_ab*)(Wfpk + (((nt * 4 + ks) * 64 + lane) << 3));
            acca[nt] = __builtin_amdgcn_mfma_f32_16x16x32_bf16(a, bf, acca[nt], 0, 0, 0);
        }
    }

    // hidden (C-layout) + delta head via 16-lane shuffle reduce, all fp32
    float hc[8][4];
    float dJD[4][3];
#pragma unroll
    for (int j = 0; j < 4; ++j)
#pragma unroll
        for (int d = 0; d < 3; ++d) dJD[j][d] = 0.f;
#pragma unroll
    for (int nt = 0; nt < 8; ++nt) {
        int col = nt * 16 + (lane & 15);
        float b1 = h_b1[col];
        float w20 = h_w2[col * 3 + 0];
        float w21 = h_w2[col * 3 + 1];
        float w22 = h_w2[col * 3 + 2];
#pragma unroll
        for (int j = 0; j < 4; ++j) {
            float h = fmaxf(acch[nt][j] + b1, 0.f);
            hc[nt][j] = h;
            dJD[j][0] += h * w20;
            dJD[j][1] += h * w21;
            dJD[j][2] += h * w22;
        }
    }
#pragma unroll
    for (int m = 1; m < 16; m <<= 1)
#pragma unroll
        for (int j = 0; j < 4; ++j)
#pragma unroll
            for (int d = 0; d < 3; ++d)
                dJD[j][d] += __shfl_xor(dJD[j][d], m);

    float delta[4][3];
#pragma unroll
    for (int j = 0; j < 4; ++j)
#pragma unroll
        for (int d = 0; d < 3; ++d)
            delta[j][d] = tanhf(dJD[j][d] + h_b2[d]);

    // epilogue: per lane 4 rows x 8 col-tiles
#pragma unroll
    for (int j = 0; j < 4; ++j) {
        int grow = row0 + wr0 + ((lane >> 4) << 2) + j;
        if (grow >= M) continue;
        float p0 = pos[(size_t)grow * 3 + 0];
        float p1 = pos[(size_t)grow * 3 + 1];
        float p2 = pos[(size_t)grow * 3 + 2];
        float d0 = delta[j][0], d1 = delta[j][1], d2 = delta[j][2];
#pragma unroll
        for (int nt = 0; nt < 8; ++nt) {
            int col = nt * 16 + (lane & 15);
            float w0 = f_w[col], w1 = f_w[128 + col], w2 = f_w[256 + col];
            float pw = p0 * w0 + p1 * w1 + p2 * w2;
            float dw = d0 * w0 + d1 * w1 + d2 * w2;
            A2h[(size_t)grow * 128 + col] = f2b(acca[nt][j] + pw);
            Bvh[(size_t)grow * 128 + col] = f2b(f_b[col] + dw - pw);
        }
    }
    (void)hc;
}

// ---------------------------------------------------------------------------
// counting sort by dst: hist -> hierarchical scan (3 kernels) -> scatter
// ---------------------------------------------------------------------------
__global__ __launch_bounds__(TPB) void hist_kernel(
    const int* __restrict__ ei, int* __restrict__ counts, int E)
{
    int e = blockIdx.x * TPB + threadIdx.x;
    if (e < E) atomicAdd(&counts[ei[E + e]], 1);
}

__global__ __launch_bounds__(TPB) void scan1_kernel(
    const int* __restrict__ counts, int* __restrict__ partial)
{
    int tid = threadIdx.x;
    int4 v = *(const int4*)(counts + (size_t)blockIdx.x * 1024 + tid * 4);
    int s = v.x + v.y + v.z + v.w;
#pragma unroll
    for (int m = 1; m < 64; m <<= 1) s += __shfl_xor(s, m);
    __shared__ int ws[4];
    if ((tid & 63) == 0) ws[tid >> 6] = s;
    __syncthreads();
    if (tid == 0) partial[blockIdx.x] = ws[0] + ws[1] + ws[2] + ws[3];
}

__global__ __launch_bounds__(64) void scan2_kernel(
    int* __restrict__ partial, int* __restrict__ offs, int nblk, int M)
{
    int tid = threadIdx.x;
    int v = (tid < nblk) ? partial[tid] : 0;
    int s = v;
#pragma unroll
    for (int d = 1; d < 64; d <<= 1) {
        int t = __shfl_up(s, d);
        if (tid >= d) s += t;
    }
    if (tid < nblk) partial[tid] = s - v;   // exclusive
    if (tid == 63) offs[M] = s;             // total = E
}

__global__ __launch_bounds__(TPB) void scan3_kernel(
    const int* __restrict__ counts, const int* __restrict__ partial,
    int* __restrict__ offs, int* __restrict__ cursor, int M)
{
    int tid = threadIdx.x;
    int base = blockIdx.x * 1024 + tid * 4;
    int4 v = *(const int4*)(counts + base);
    int s = v.x + v.y + v.z + v.w;
    int incl = s;
#pragma unroll
    for (int d = 1; d < 64; d <<= 1) {
        int t = __shfl_up(incl, d);
        if ((tid & 63) >= d) incl += t;
    }
    __shared__ int ws[4];
    if ((tid & 63) == 63) ws[tid >> 6] = incl;
    __syncthreads();
    int wp = 0;
#pragma unroll
    for (int w = 0; w < 4; ++w) wp += (w < (tid >> 6)) ? ws[w] : 0;
    int run = partial[blockIdx.x] + wp + incl - s;
    int vv[4] = {v.x, v.y, v.z, v.w};
#pragma unroll
    for (int i = 0; i < 4; ++i) {
        if (base + i < M) { offs[base + i] = run; cursor[base + i] = run; }
        run += vv[i];
    }
}

__global__ __launch_bounds__(TPB) void scatter_kernel(
    const int* __restrict__ ei, int* __restrict__ cursor,
    int* __restrict__ ssrc, int E)
{
    int e = blockIdx.x * TPB + threadIdx.x;
    if (e >= E) return;
    int d = ei[E + e];
    int p = atomicAdd(&cursor[d], 1);
    ssrc[p] = ei[e];
}

// ---------------------------------------------------------------------------
// segmented reduce (bf16 inputs, fp32 accum): one wave per dst row, 2 cols/lane
// ---------------------------------------------------------------------------
__global__ __launch_bounds__(TPB) void reduce_kernel(
    const int* __restrict__ offs, const int* __restrict__ ssrc,
    const ushort* __restrict__ A2h, const ushort* __restrict__ Bvh,
    float* __restrict__ out, int M)
{
    int row = blockIdx.x * 4 + (threadIdx.x >> 6);
    if (row >= M) return;
    int lane = threadIdx.x & 63;
    int c = lane * 2;
    uint bu = *(const uint*)(Bvh + (size_t)row * 128 + c);
    float b0 = b2f_lo(bu), b1 = b2f_hi(bu);
    float a0 = 0.f, a1 = 0.f;
    int k  = offs[row];
    int k1 = offs[row + 1];
    for (; k + 1 < k1; k += 2) {
        int s0 = ssrc[k];
        int s1 = ssrc[k + 1];
        uint u0 = *(const uint*)(A2h + (size_t)s0 * 128 + c);
        uint u1 = *(const uint*)(A2h + (size_t)s1 * 128 + c);
        a0 += fmaxf(b2f_lo(u0) + b0, 0.f) + fmaxf(b2f_lo(u1) + b0, 0.f);
        a1 += fmaxf(b2f_hi(u0) + b1, 0.f) + fmaxf(b2f_hi(u1) + b1, 0.f);
    }
    if (k < k1) {
        uint u0 = *(const uint*)(A2h + (size_t)ssrc[k] * 128 + c);
        a0 += fmaxf(b2f_lo(u0) + b0, 0.f);
        a1 += fmaxf(b2f_hi(u0) + b1, 0.f);
    }
    float2 r; r.x = a0; r.y = a1;
    *(float2*)(out + (size_t)row * 128 + c) = r;
}

// ---------------------------------------------------------------------------
// post: out = relu(aggr@g_w1+g_b1)@g_w2 + g_b2 + x   (MFMA, in-place on out)
// ---------------------------------------------------------------------------
__global__ __launch_bounds__(TPB) void post_kernel(
    const float* __restrict__ x,
    const short* __restrict__ G1pk, const float* __restrict__ g_b1,
    const short* __restrict__ G2pk, const float* __restrict__ g_b2,
    float* __restrict__ out, int M)
{
    __shared__ short s1[64 * 128];
    __shared__ short s2[64 * 128];
    const int tid  = threadIdx.x;
    const int lane = tid & 63;
    const int wave = tid >> 6;
    const int row0 = blockIdx.x * 64;

    // stage aggr -> bf16 LDS swizzled
#pragma unroll
    for (int i = 0; i < 4; ++i) {
        int id = i * TPB + tid;
        int r = id >> 4, slot = id & 15;
        int gr = row0 + r; if (gr >= M) gr = M - 1;
        const float* px = out + (size_t)gr * 128 + slot * 8;
        float4 v0 = *(const float4*)px;
        float4 v1 = *(const float4*)(px + 4);
        frag_ab f;
        f[0] = (short)f2b(v0.x); f[1] = (short)f2b(v0.y);
        f[2] = (short)f2b(v0.z); f[3] = (short)f2b(v0.w);
        f[4] = (short)f2b(v1.x); f[5] = (short)f2b(v1.y);
        f[6] = (short)f2b(v1.z); f[7] = (short)f2b(v1.w);
        *(frag_ab*)(s1 + r * 128 + ((slot ^ (r & 7)) << 3)) = f;
    }
    __syncthreads();

    const int wr0 = wave * 16;
    f32x4 acc[8];
#pragma unroll
    for (int nt = 0; nt < 8; ++nt) acc[nt] = (f32x4)0.f;
#pragma unroll
    for (int ks = 0; ks < 4; ++ks) {
        int arow  = wr0 + (lane & 15);
        int aslot = ks * 4 + (lane >> 4);
        frag_ab a = *(const frag_ab*)(s1 + arow * 128 + ((aslot ^ (arow & 7)) << 3));
#pragma unroll
        for (int nt = 0; nt < 8; ++nt) {
            frag_ab b = *(const frag_ab*)(G1pk + (((nt * 4 + ks) * 64 + lane) << 3));
            acc[nt] = __builtin_amdgcn_mfma_f32_16x16x32_bf16(a, b, acc[nt], 0, 0, 0);
        }
    }

    // hidden2 = relu(acc+g_b1) -> bf16 -> s2 in A-layout (swizzled)
#pragma unroll
    for (int nt = 0; nt < 8; ++nt) {
        int col = nt * 16 + (lane & 15);
        float b1 = g_b1[col];
        int slot = col >> 3, within = col & 7;
#pragma unroll
        for (int j = 0; j < 4; ++j) {
            int row = wr0 + ((lane >> 4) << 2) + j;
            s2[row * 128 + ((slot ^ (row & 7)) << 3) + within] =
                (short)f2b(fmaxf(acc[nt][j] + b1, 0.f));
        }
    }
    __syncthreads();

    f32x4 acc2[8];
#pragma unroll
    for (int nt = 0; nt < 8; ++nt) acc2[nt] = (f32x4)0.f;
#pragma unroll
    for (int ks = 0; ks < 4; ++ks) {
        int arow  = wr0 + (lane & 15);
        int aslot = ks * 4 + (lane >> 4);
        frag_ab a = *(const frag_ab*)(s2 + arow * 128 + ((aslot ^ (arow & 7)) << 3));
#pragma unroll
        for (int nt = 0; nt < 8; ++nt) {
            frag_ab b = *(const frag_ab*)(G2pk + (((nt * 4 + ks) * 64 + lane) << 3));
            acc2[nt] = __builtin_amdgcn_mfma_f32_16x16x32_bf16(a, b, acc2[nt], 0, 0, 0);
        }
    }

#pragma unroll
    for (int j = 0; j < 4; ++j) {
        int grow = row0 + wr0 + ((lane >> 4) << 2) + j;
        if (grow >= M) continue;
#pragma unroll
        for (int nt = 0; nt < 8; ++nt) {
            int col = nt * 16 + (lane & 15);
            out[(size_t)grow * 128 + col] =
                acc2[nt][j] + g_b2[col] + x[(size_t)grow * 128 + col];
        }
    }
}

extern "C" void kernel_launch(void* const* d_in, const int* in_sizes, int n_in,
                              void* d_out, int out_size, void* d_ws, size_t ws_size,
                              hipStream_t stream)
{
    const float* x    = (const float*)d_in[0];
    const float* pos  = (const float*)d_in[1];
    const int*   ei   = (const int*)d_in[2];
    const float* h_w1 = (const float*)d_in[3];
    const float* h_b1 = (const float*)d_in[4];
    const float* h_w2 = (const float*)d_in[5];
    const float* h_b2 = (const float*)d_in[6];
    const float* f_w  = (const float*)d_in[7];
    const float* f_b  = (const float*)d_in[8];
    const float* g_w1 = (const float*)d_in[9];
    const float* g_b1 = (const float*)d_in[10];
    const float* g_w2 = (const float*)d_in[11];
    const float* g_b2 = (const float*)d_in[12];

    const int M = in_sizes[1] / 3;       // 50000
    const int E = in_sizes[2] / 2;       // 600000
    const int nblk = (M + 1023) / 1024;  // 49
    const int Mpad = nblk * 1024;

    ushort* A2h   = (ushort*)d_ws;                         // [M][128] bf16
    ushort* Bvh   = A2h + (size_t)M * 128;                 // [M][128] bf16
    short* W1pk   = (short*)(Bvh + (size_t)M * 128);       // 16384
    short* Wfpk   = W1pk + 16384;
    short* G1pk   = Wfpk + 16384;
    short* G2pk   = G1pk + 16384;
    int* counts   = (int*)(G2pk + 16384);                  // [Mpad]
    int* partial  = counts + Mpad;                         // [64]
    int* offs     = partial + 64;                          // [M+1]
    int* cursor   = offs + (M + 1);                        // [M]
    int* ssrc     = cursor + M;                            // [E]
    float* out    = (float*)d_out;

    const int nb = (M + 63) / 64;

    hipMemsetAsync(counts, 0, (size_t)Mpad * sizeof(int), stream);
    pack_kernel<<<dim3(8, 4), TPB, 0, stream>>>(h_w1, f_w, g_w1, g_w2,
                                                W1pk, Wfpk, G1pk, G2pk);
    pre_kernel<<<nb, TPB, 0, stream>>>(x, pos, W1pk, h_b1, h_w2, h_b2,
                                       Wfpk, f_w, f_b, A2h, Bvh, M);
    hist_kernel<<<(E + TPB - 1) / TPB, TPB, 0, stream>>>(ei, counts, E);
    scan1_kernel<<<nblk, TPB, 0, stream>>>(counts, partial);
    scan2_kernel<<<1, 64, 0, stream>>>(partial, offs, nblk, M);
    scan3_kernel<<<nblk, TPB, 0, stream>>>(counts, partial, offs, cursor, M);
    scatter_kernel<<<(E + TPB - 1) / TPB, TPB, 0, stream>>>(ei, cursor, ssrc, E);
    reduce_kernel<<<(M + 3) / 4, TPB, 0, stream>>>(offs, ssrc, A2h, Bvh, out, M);
    post_kernel<<<nb, TPB, 0, stream>>>(x, G1pk, g_b1, G2pk, g_b2, out, M);
}